// Round 1
// baseline (992.173 us; speedup 1.0000x reference)
//
#include <hip/hip_runtime.h>
#include <stdint.h>

#define B_ 64
#define S_ 2048
#define E_ 1024   // ENC_DIM (= K of main GEMM)
#define D_ 1024   // DEC_DIM
#define A_ 512    // ATT_DIM (= N of main GEMM)
#define M_ (B_*S_)

typedef __attribute__((ext_vector_type(8))) short short8;
typedef __attribute__((ext_vector_type(4))) float floatx4;

typedef __attribute__((address_space(3))) void       lds_void_t;
typedef const __attribute__((address_space(1))) void gbl_void_t;

__device__ __forceinline__ unsigned short f2bf(float f) {
    union { float f; uint32_t u; } v; v.f = f;
    uint32_t u = v.u;
    return (unsigned short)((u + 0x7FFF + ((u >> 16) & 1)) >> 16);  // RNE
}

// ---------------- W_enc fp32 -> bf16 (ws) ----------------
__global__ void k_convert_wenc(const float* __restrict__ wenc,
                               unsigned short* __restrict__ out) {
    int i = blockIdx.x * 256 + threadIdx.x;          // 131072 threads x 4 elems
    float4 v = ((const float4*)wenc)[i];
    ushort4 o;
    o.x = f2bf(v.x); o.y = f2bf(v.y); o.z = f2bf(v.z); o.w = f2bf(v.w);
    ((ushort4*)out)[i] = o;
}

// ---------------- dec_feat = decoder_hidden @ W_dec^T  [B, A] ----------------
__global__ void k_dec_feat(const float* __restrict__ dh,
                           const float* __restrict__ wdec,
                           float* __restrict__ df) {
    __shared__ float h[D_];
    int b = blockIdx.x, t = threadIdx.x;
    for (int i = t; i < D_/4; i += 256)
        ((float4*)h)[i] = ((const float4*)(dh + (size_t)b * D_))[i];
    __syncthreads();
    #pragma unroll
    for (int rep = 0; rep < 2; ++rep) {
        int a = t + rep * 256;
        const float4* wr = (const float4*)(wdec + (size_t)a * D_);
        float acc = 0.f;
        for (int k4 = 0; k4 < D_/4; ++k4) {
            float4 w = wr[k4];
            float4 x = ((float4*)h)[k4];
            acc += w.x*x.x + w.y*x.y + w.z*x.z + w.w*x.w;
        }
        df[b * A_ + a] = acc;
    }
}

// ---------------- fused scores GEMM ----------------
// scores[m] = sum_n W_energy[n] * tanh( (enc @ W_enc^T)[m,n] + dec_feat[b,n] )
// block tile: 64 rows x 512 cols (full N), K=1024 in BK=32 steps.
#define BM 64
#define BK 32

__global__ __launch_bounds__(256, 2) void k_scores(
    const float* __restrict__ enc,            // [M, E] fp32
    const unsigned short* __restrict__ wenc,  // [A, E] bf16 (B^T layout)
    const float* __restrict__ df,             // [B, A]
    const float* __restrict__ wE,             // [A]
    float* __restrict__ scores)               // [M]
{
    __shared__ unsigned short As[BM * BK];    // 4 KB
    __shared__ unsigned short Bs[A_ * BK];    // 32 KB
    __shared__ float ps[4][BM];               // per-wave partial scores

    const int tid  = threadIdx.x;
    const int wave = tid >> 6;
    const int lane = tid & 63;
    const int m0   = blockIdx.x * BM;
    const int b    = m0 >> 11;                // 2048 rows per batch, 64 | 2048

    floatx4 acc[4][8];
    #pragma unroll
    for (int i = 0; i < 4; ++i)
        #pragma unroll
        for (int j = 0; j < 8; ++j) acc[i][j] = (floatx4)0.f;

    const int m_a = tid >> 2;                 // 0..63 (A-staging row)
    const int k_a = (tid & 3) * 8;            // 0,8,16,24
    const float* aptr = enc + (size_t)(m0 + m_a) * E_ + k_a;

    const int n0w   = wave * 128;
    const int row16 = lane >> 4;              // 0..3
    const int col   = lane & 15;

    for (int kt = 0; kt < E_ / BK; ++kt) {
        if (kt) __syncthreads();
        // ---- stage A (fp32 -> bf16 -> LDS) ----
        float4 a0 = *(const float4*)(aptr + kt * BK);
        float4 a1 = *(const float4*)(aptr + kt * BK + 4);
        short8 apk;
        apk[0] = (short)f2bf(a0.x); apk[1] = (short)f2bf(a0.y);
        apk[2] = (short)f2bf(a0.z); apk[3] = (short)f2bf(a0.w);
        apk[4] = (short)f2bf(a1.x); apk[5] = (short)f2bf(a1.y);
        apk[6] = (short)f2bf(a1.z); apk[7] = (short)f2bf(a1.w);
        *(short8*)(&As[m_a * BK + k_a]) = apk;
        // ---- stage B (bf16 ws -> LDS, async 16B) ----
        #pragma unroll
        for (int r = 0; r < 8; ++r) {
            int idx = r * 256 + tid;
            int n   = idx >> 2;
            int kq  = idx & 3;
            const unsigned short* g = wenc + (size_t)n * E_ + kt * BK + kq * 8;
            unsigned short* l = &Bs[(size_t)(r * 256 + wave * 64) * 8];
            __builtin_amdgcn_global_load_lds((gbl_void_t*)g, (lds_void_t*)l, 16, 0, 0);
        }
        __syncthreads();
        // ---- fragments + MFMA ----
        short8 af[4];
        #pragma unroll
        for (int mt = 0; mt < 4; ++mt)
            af[mt] = *(const short8*)(&As[(mt * 16 + col) * BK + row16 * 8]);
        short8 bfr[8];
        #pragma unroll
        for (int nt = 0; nt < 8; ++nt)
            bfr[nt] = *(const short8*)(&Bs[(n0w + nt * 16 + col) * BK + row16 * 8]);
        #pragma unroll
        for (int mt = 0; mt < 4; ++mt)
            #pragma unroll
            for (int nt = 0; nt < 8; ++nt)
                acc[mt][nt] = __builtin_amdgcn_mfma_f32_16x16x32_bf16(
                    af[mt], bfr[nt], acc[mt][nt], 0, 0, 0);
    }

    // ---- epilogue: tanh(acc + df) * wE, reduce over n within block ----
    float part[4][4];
    #pragma unroll
    for (int mt = 0; mt < 4; ++mt)
        #pragma unroll
        for (int r = 0; r < 4; ++r) part[mt][r] = 0.f;

    #pragma unroll
    for (int nt = 0; nt < 8; ++nt) {
        int n   = n0w + nt * 16 + col;
        float d = df[b * A_ + n];
        float w = wE[n];
        #pragma unroll
        for (int mt = 0; mt < 4; ++mt)
            #pragma unroll
            for (int r = 0; r < 4; ++r) {
                float x  = acc[mt][nt][r] + d;
                float ex = __expf(2.f * x);
                float th = 1.f - 2.f / (ex + 1.f);   // tanh(x)
                part[mt][r] += w * th;
            }
    }
    // reduce across the 16 columns held by lanes sharing a row group
    #pragma unroll
    for (int mt = 0; mt < 4; ++mt)
        #pragma unroll
        for (int r = 0; r < 4; ++r) {
            float v = part[mt][r];
            v += __shfl_xor(v, 1);
            v += __shfl_xor(v, 2);
            v += __shfl_xor(v, 4);
            v += __shfl_xor(v, 8);
            part[mt][r] = v;
        }
    if (col == 0) {
        #pragma unroll
        for (int mt = 0; mt < 4; ++mt)
            #pragma unroll
            for (int r = 0; r < 4; ++r)
                ps[wave][mt * 16 + row16 * 4 + r] = part[mt][r];
    }
    __syncthreads();
    if (tid < BM)
        scores[m0 + tid] = ps[0][tid] + ps[1][tid] + ps[2][tid] + ps[3][tid];
}

// ---------------- masked softmax over S per batch row ----------------
__global__ void k_softmax(const float* __restrict__ scores,
                          const int* __restrict__ mask,
                          float* __restrict__ weights) {
    __shared__ float red[8];
    int b = blockIdx.x, t = threadIdx.x;
    float v[8];
    #pragma unroll
    for (int i = 0; i < 8; ++i) {
        int s = t + i * 256;
        float x = scores[b * S_ + s];
        v[i] = mask[b * S_ + s] ? -3.402823466e38f : x;   // mask==True -> finfo.min
    }
    float mx = v[0];
    #pragma unroll
    for (int i = 1; i < 8; ++i) mx = fmaxf(mx, v[i]);
    #pragma unroll
    for (int o = 32; o; o >>= 1) mx = fmaxf(mx, __shfl_xor(mx, o));
    if ((t & 63) == 0) red[t >> 6] = mx;
    __syncthreads();
    mx = fmaxf(fmaxf(red[0], red[1]), fmaxf(red[2], red[3]));

    float e[8], sum = 0.f;
    #pragma unroll
    for (int i = 0; i < 8; ++i) { e[i] = __expf(v[i] - mx); sum += e[i]; }
    #pragma unroll
    for (int o = 32; o; o >>= 1) sum += __shfl_xor(sum, o);
    if ((t & 63) == 0) red[4 + (t >> 6)] = sum;
    __syncthreads();
    sum = red[4] + red[5] + red[6] + red[7];
    float inv = 1.f / sum;
    #pragma unroll
    for (int i = 0; i < 8; ++i)
        weights[b * S_ + t + i * 256] = e[i] * inv;
}

// ---------------- context = weights @ encoder_outputs ----------------
__global__ void k_context(const float* __restrict__ enc,
                          const float* __restrict__ weights,
                          float* __restrict__ ctx) {
    int b  = blockIdx.x >> 4;     // 16 s-chunks of 128
    int sc = blockIdx.x & 15;
    int t  = threadIdx.x;
    const float* ep = enc + (size_t)b * S_ * E_ + (size_t)sc * 128 * E_ + t * 4;
    const float* wp = weights + b * S_ + sc * 128;
    float4 acc = {0.f, 0.f, 0.f, 0.f};
    for (int s = 0; s < 128; ++s) {
        float w  = wp[s];
        float4 x = *(const float4*)(ep + (size_t)s * E_);
        acc.x += w * x.x; acc.y += w * x.y; acc.z += w * x.z; acc.w += w * x.w;
    }
    float* o = ctx + (size_t)b * E_ + t * 4;
    atomicAdd(o + 0, acc.x); atomicAdd(o + 1, acc.y);
    atomicAdd(o + 2, acc.z); atomicAdd(o + 3, acc.w);
}

extern "C" void kernel_launch(void* const* d_in, const int* in_sizes, int n_in,
                              void* d_out, int out_size, void* d_ws, size_t ws_size,
                              hipStream_t stream) {
    const float* dh   = (const float*)d_in[0];   // [64,1024]
    const float* enc  = (const float*)d_in[1];   // [64,2048,1024]
    const int*   mask = (const int*)  d_in[2];   // [64,2048] bool->int
    const float* wenc = (const float*)d_in[3];   // [512,1024]
    const float* wdec = (const float*)d_in[4];   // [512,1024]
    const float* wE   = (const float*)d_in[5];   // [1,512]

    float* out     = (float*)d_out;
    float* ctx     = out;                 // [64*1024]
    float* weights = out + B_ * E_;       // [64*2048]

    unsigned short* wenc_bf = (unsigned short*)d_ws;                       // 1 MB
    float* df     = (float*)((char*)d_ws + (size_t)A_ * E_ * 2);           // 128 KB
    float* scores = df + B_ * A_;                                          // 512 KB

    hipMemsetAsync(ctx, 0, (size_t)B_ * E_ * sizeof(float), stream);
    k_convert_wenc<<<512, 256, 0, stream>>>(wenc, wenc_bf);
    k_dec_feat<<<B_, 256, 0, stream>>>(dh, wdec, df);
    k_scores<<<M_ / BM, 256, 0, stream>>>(enc, wenc_bf, df, wE, scores);
    k_softmax<<<B_, 256, 0, stream>>>(scores, mask, weights);
    k_context<<<B_ * 16, 256, 0, stream>>>(enc, weights, ctx);
}

// Round 2
// 902.878 us; speedup vs baseline: 1.0989x; 1.0989x over previous
//
#include <hip/hip_runtime.h>
#include <stdint.h>

#define B_ 64
#define S_ 2048
#define E_ 1024   // ENC_DIM (= K of main GEMM)
#define D_ 1024   // DEC_DIM
#define A_ 512    // ATT_DIM (= N of main GEMM)
#define M_ (B_*S_)

typedef __attribute__((ext_vector_type(8))) short short8;
typedef __attribute__((ext_vector_type(4))) float floatx4;

typedef __attribute__((address_space(3))) void       lds_void_t;
typedef const __attribute__((address_space(1))) void gbl_void_t;

__device__ __forceinline__ unsigned short f2bf(float f) {
    union { float f; uint32_t u; } v; v.f = f;
    uint32_t u = v.u;
    return (unsigned short)((u + 0x7FFF + ((u >> 16) & 1)) >> 16);  // RNE
}

// ---------------- W_enc fp32 -> bf16, shuffled to staging layout ----------------
// wencS logical layout: [kt(32)][kq(4)][n(512)][e(8)] bf16, i.e. 16B slot
// (kt*2048 + kq*512 + n) holds wenc[n][kt*32 + kq*8 .. +7].
__global__ void k_convert_wenc(const float* __restrict__ wenc,
                               unsigned short* __restrict__ wencS) {
    int slot = blockIdx.x * 256 + threadIdx.x;   // 65536 slots
    int kt = slot >> 11;
    int kq = (slot >> 9) & 3;
    int n  = slot & 511;
    const float4* src = (const float4*)(wenc + (size_t)n * E_ + kt * 32 + kq * 8);
    float4 a = src[0], b = src[1];
    short8 o;
    o[0] = (short)f2bf(a.x); o[1] = (short)f2bf(a.y);
    o[2] = (short)f2bf(a.z); o[3] = (short)f2bf(a.w);
    o[4] = (short)f2bf(b.x); o[5] = (short)f2bf(b.y);
    o[6] = (short)f2bf(b.z); o[7] = (short)f2bf(b.w);
    *(short8*)(wencS + (size_t)slot * 8) = o;
}

// ---------------- dec_feat = decoder_hidden @ W_dec^T  [B, A] ----------------
// 512 blocks: (b, 64-wide a-chunk); thread = (a, quarter-K); 4-lane shfl reduce.
__global__ void k_dec_feat(const float* __restrict__ dh,
                           const float* __restrict__ wdec,
                           float* __restrict__ df) {
    __shared__ float h[1056];                    // 4 kq-chunks, 264-float stride (pad 8)
    int b  = blockIdx.x >> 3;
    int a0 = (blockIdx.x & 7) * 64;
    int t  = threadIdx.x;
    {
        float4 v = ((const float4*)(dh + (size_t)b * D_))[t];
        int e0 = t * 4;
        *(float4*)(h + (e0 >> 8) * 264 + (e0 & 255)) = v;
    }
    __syncthreads();
    int a  = a0 + (t >> 2);
    int kq = t & 3;
    const float4* wr = (const float4*)(wdec + (size_t)a * D_ + kq * 256);
    const float4* hh = (const float4*)(h + kq * 264);
    float acc = 0.f;
    #pragma unroll 8
    for (int k4 = 0; k4 < 64; ++k4) {
        float4 w = wr[k4];
        float4 x = hh[k4];
        acc += w.x*x.x + w.y*x.y + w.z*x.z + w.w*x.w;
    }
    acc += __shfl_xor(acc, 1);
    acc += __shfl_xor(acc, 2);
    if ((t & 3) == 0) df[b * A_ + a] = acc;
}

// ---------------- fused scores GEMM ----------------
// scores[m] = sum_n W_energy[n] * tanh( (enc @ W_enc^T)[m,n] + dec_feat[b,n] )
// block tile: 64 rows x 512 cols (full N), K=1024 in BK=32 steps.
#define BM 64
#define BK 32
#define AROW 40   // padded A row: 32 + 8 elems = 80 B (5 x 16B) -> conflict-free frag reads

__global__ __launch_bounds__(256, 2) void k_scores(
    const float* __restrict__ enc,            // [M, E] fp32
    const unsigned short* __restrict__ wencS, // shuffled bf16 (see k_convert_wenc)
    const float* __restrict__ df,             // [B, A]
    const float* __restrict__ wE,             // [A]
    float* __restrict__ scores)               // [M]
{
    __shared__ unsigned short As[BM * AROW];  // 5 KB, layout [m][k (padded)]
    __shared__ unsigned short Bs[4 * 512 * 8];// 32 KB, layout [kq][n][e]
    __shared__ float ps[4][BM];

    const int tid  = threadIdx.x;
    const int wave = tid >> 6;
    const int lane = tid & 63;
    const int m0   = blockIdx.x * BM;
    const int b    = m0 >> 11;

    floatx4 acc[4][8];
    #pragma unroll
    for (int i = 0; i < 4; ++i)
        #pragma unroll
        for (int j = 0; j < 8; ++j) acc[i][j] = (floatx4)0.f;

    const int m_a = tid >> 2;                 // 0..63
    const int j_a = tid & 3;                  // k-quad 0..3
    const float* aptr = enc + (size_t)(m0 + m_a) * E_ + j_a * 8;

    const int n0w   = wave * 128;
    const int row16 = lane >> 4;              // 0..3  (= kq of fragment)
    const int col   = lane & 15;

    for (int kt = 0; kt < E_ / BK; ++kt) {
        if (kt) __syncthreads();
        // ---- A global loads first (latency), then B DMA, then A convert+write ----
        float4 a0 = *(const float4*)(aptr + kt * BK);
        float4 a1 = *(const float4*)(aptr + kt * BK + 4);
        // ---- stage B: lane-linear slots == [kq][n][e] layout ----
        #pragma unroll
        for (int r = 0; r < 8; ++r) {
            int s = r * 256 + tid;            // slot within this kt
            const unsigned short* g = wencS + ((size_t)kt * 2048 + s) * 8;
            unsigned short* l = &Bs[(size_t)(r * 256 + wave * 64) * 8];
            __builtin_amdgcn_global_load_lds((gbl_void_t*)g, (lds_void_t*)l, 16, 0, 0);
        }
        // ---- A fp32 -> bf16 -> LDS ----
        short8 apk;
        apk[0] = (short)f2bf(a0.x); apk[1] = (short)f2bf(a0.y);
        apk[2] = (short)f2bf(a0.z); apk[3] = (short)f2bf(a0.w);
        apk[4] = (short)f2bf(a1.x); apk[5] = (short)f2bf(a1.y);
        apk[6] = (short)f2bf(a1.z); apk[7] = (short)f2bf(a1.w);
        *(short8*)(&As[m_a * AROW + j_a * 8]) = apk;
        __syncthreads();
        // ---- fragments + MFMA ----
        short8 af[4];
        #pragma unroll
        for (int mt = 0; mt < 4; ++mt)
            af[mt] = *(const short8*)(&As[(mt * 16 + col) * AROW + row16 * 8]);
        short8 bfr[8];
        #pragma unroll
        for (int nt = 0; nt < 8; ++nt)
            bfr[nt] = *(const short8*)(&Bs[(size_t)(row16 * 512 + n0w + nt * 16 + col) * 8]);
        #pragma unroll
        for (int mt = 0; mt < 4; ++mt)
            #pragma unroll
            for (int nt = 0; nt < 8; ++nt)
                acc[mt][nt] = __builtin_amdgcn_mfma_f32_16x16x32_bf16(
                    af[mt], bfr[nt], acc[mt][nt], 0, 0, 0);
    }

    // ---- epilogue: tanh(acc + df) * wE, reduce over n ----
    float part[4][4];
    #pragma unroll
    for (int mt = 0; mt < 4; ++mt)
        #pragma unroll
        for (int r = 0; r < 4; ++r) part[mt][r] = 0.f;

    #pragma unroll
    for (int nt = 0; nt < 8; ++nt) {
        int n   = n0w + nt * 16 + col;
        float d = df[b * A_ + n];
        float w = wE[n];
        #pragma unroll
        for (int mt = 0; mt < 4; ++mt)
            #pragma unroll
            for (int r = 0; r < 4; ++r) {
                float x  = acc[mt][nt][r] + d;
                float ex = __expf(2.f * x);
                float th = 1.f - 2.f / (ex + 1.f);   // tanh(x)
                part[mt][r] += w * th;
            }
    }
    #pragma unroll
    for (int mt = 0; mt < 4; ++mt)
        #pragma unroll
        for (int r = 0; r < 4; ++r) {
            float v = part[mt][r];
            v += __shfl_xor(v, 1);
            v += __shfl_xor(v, 2);
            v += __shfl_xor(v, 4);
            v += __shfl_xor(v, 8);
            part[mt][r] = v;
        }
    if (col == 0) {
        #pragma unroll
        for (int mt = 0; mt < 4; ++mt)
            #pragma unroll
            for (int r = 0; r < 4; ++r)
                ps[wave][mt * 16 + row16 * 4 + r] = part[mt][r];
    }
    __syncthreads();
    if (tid < BM)
        scores[m0 + tid] = ps[0][tid] + ps[1][tid] + ps[2][tid] + ps[3][tid];
}

// ---------------- masked softmax over S per batch row ----------------
__global__ void k_softmax(const float* __restrict__ scores,
                          const int* __restrict__ mask,
                          float* __restrict__ weights) {
    __shared__ float red[8];
    int b = blockIdx.x, t = threadIdx.x;
    float v[8];
    #pragma unroll
    for (int i = 0; i < 8; ++i) {
        int s = t + i * 256;
        float x = scores[b * S_ + s];
        v[i] = mask[b * S_ + s] ? -3.402823466e38f : x;   // mask==True -> finfo.min
    }
    float mx = v[0];
    #pragma unroll
    for (int i = 1; i < 8; ++i) mx = fmaxf(mx, v[i]);
    #pragma unroll
    for (int o = 32; o; o >>= 1) mx = fmaxf(mx, __shfl_xor(mx, o));
    if ((t & 63) == 0) red[t >> 6] = mx;
    __syncthreads();
    mx = fmaxf(fmaxf(red[0], red[1]), fmaxf(red[2], red[3]));

    float e[8], sum = 0.f;
    #pragma unroll
    for (int i = 0; i < 8; ++i) { e[i] = __expf(v[i] - mx); sum += e[i]; }
    #pragma unroll
    for (int o = 32; o; o >>= 1) sum += __shfl_xor(sum, o);
    if ((t & 63) == 0) red[4 + (t >> 6)] = sum;
    __syncthreads();
    sum = red[4] + red[5] + red[6] + red[7];
    float inv = 1.f / sum;
    #pragma unroll
    for (int i = 0; i < 8; ++i)
        weights[b * S_ + t + i * 256] = e[i] * inv;
}

// ---------------- context = weights @ encoder_outputs ----------------
// 512 blocks = (b, 8 s-chunks of 256). 8-deep load batches for MLP.
__global__ void k_context(const float* __restrict__ enc,
                          const float* __restrict__ weights,
                          float* __restrict__ ctx) {
    int b  = blockIdx.x >> 3;
    int sc = blockIdx.x & 7;
    int t  = threadIdx.x;
    const float4* ep = (const float4*)(enc + (size_t)b * S_ * E_ + (size_t)sc * 256 * E_) + t;
    const float*  wp = weights + b * S_ + sc * 256;
    float4 acc = {0.f, 0.f, 0.f, 0.f};
    for (int s0 = 0; s0 < 256; s0 += 8) {
        float4 x[8];
        #pragma unroll
        for (int i = 0; i < 8; ++i)
            x[i] = ep[(size_t)(s0 + i) * (E_ / 4)];
        #pragma unroll
        for (int i = 0; i < 8; ++i) {
            float w = wp[s0 + i];
            acc.x += w * x[i].x; acc.y += w * x[i].y;
            acc.z += w * x[i].z; acc.w += w * x[i].w;
        }
    }
    float* o = ctx + (size_t)b * E_ + t * 4;
    atomicAdd(o + 0, acc.x); atomicAdd(o + 1, acc.y);
    atomicAdd(o + 2, acc.z); atomicAdd(o + 3, acc.w);
}

extern "C" void kernel_launch(void* const* d_in, const int* in_sizes, int n_in,
                              void* d_out, int out_size, void* d_ws, size_t ws_size,
                              hipStream_t stream) {
    const float* dh   = (const float*)d_in[0];   // [64,1024]
    const float* enc  = (const float*)d_in[1];   // [64,2048,1024]
    const int*   mask = (const int*)  d_in[2];   // [64,2048]
    const float* wenc = (const float*)d_in[3];   // [512,1024]
    const float* wdec = (const float*)d_in[4];   // [512,1024]
    const float* wE   = (const float*)d_in[5];   // [1,512]

    float* out     = (float*)d_out;
    float* ctx     = out;                 // [64*1024]
    float* weights = out + B_ * E_;       // [64*2048]

    unsigned short* wencS = (unsigned short*)d_ws;                         // 1 MB
    float* df     = (float*)((char*)d_ws + (size_t)A_ * E_ * 2);           // 128 KB
    float* scores = df + B_ * A_;                                          // 512 KB

    hipMemsetAsync(ctx, 0, (size_t)B_ * E_ * sizeof(float), stream);
    k_convert_wenc<<<256, 256, 0, stream>>>(wenc, wencS);
    k_dec_feat<<<B_ * 8, 256, 0, stream>>>(dh, wdec, df);
    k_scores<<<M_ / BM, 256, 0, stream>>>(enc, wencS, df, wE, scores);
    k_softmax<<<B_, 256, 0, stream>>>(scores, mask, weights);
    k_context<<<B_ * 8, 256, 0, stream>>>(enc, weights, ctx);
}